// Round 1
// baseline (275.375 us; speedup 1.0000x reference)
//
#include <hip/hip_runtime.h>

#define B_ 2
#define N_ 512
#define F_ 128
#define TJ 64
#define LDSTRIDE 136  // shorts per LDS row: 128 + 8 pad (keeps 16B align, spreads banks)

typedef __attribute__((ext_vector_type(8))) short short8;
typedef __attribute__((ext_vector_type(4))) float floatx4;

__device__ __forceinline__ float fsilu(float x) {
    float e = __expf(-x);
    return x * __builtin_amdgcn_rcpf(1.0f + e);
}

__device__ __forceinline__ unsigned short f2bf(float x) {
    unsigned u = __float_as_uint(x);
    u += 0x7fffu + ((u >> 16) & 1u);   // round-to-nearest-even
    return (unsigned short)(u >> 16);
}

// ---------------------------------------------------------------------------
// Kernel 1: precompute Hs = (h*mask) @ W1[:F], Ht = (h*mask) @ W1[F:2F],
//           bf16 transposes of edge_w2 / coord_w1, and msum[b] = sum_j mask.
// ---------------------------------------------------------------------------
__global__ void egcl_prep(const float* __restrict__ h,
                          const float* __restrict__ mask,
                          const float* __restrict__ ew1,
                          const float* __restrict__ ew2,
                          const float* __restrict__ cw1,
                          float* __restrict__ Hs, float* __restrict__ Ht,
                          unsigned short* __restrict__ W2T,
                          unsigned short* __restrict__ Wc1T,
                          float* __restrict__ msum) {
    __shared__ float sm[F_];
    const int blk = blockIdx.x;
    const int t = threadIdx.x;  // 128 threads
    if (blk < B_ * N_) {
        float mk = mask[blk];
        sm[t] = h[blk * F_ + t] * mk;
        __syncthreads();
        float s0 = 0.f, s1 = 0.f;
#pragma unroll 8
        for (int k = 0; k < F_; ++k) {
            float hv = sm[k];
            s0 += hv * ew1[k * F_ + t];
            s1 += hv * ew1[(F_ + k) * F_ + t];
        }
        Hs[blk * F_ + t] = s0;
        Ht[blk * F_ + t] = s1;
    } else if (blk < B_ * N_ + F_) {
        int n = blk - B_ * N_;
        W2T[n * F_ + t]  = f2bf(ew2[t * F_ + n]);
        Wc1T[n * F_ + t] = f2bf(cw1[t * F_ + n]);
    } else {
        for (int b = 0; b < B_; ++b) {
            float s = 0.f;
            for (int q = 0; q < N_ / 128; ++q) s += mask[b * N_ + t + q * 128];
            sm[t] = s;
            __syncthreads();
            for (int off = 64; off > 0; off >>= 1) {
                if (t < off) sm[t] += sm[t + off];
                __syncthreads();
            }
            if (t == 0) msum[b] = sm[0];
            __syncthreads();
        }
    }
}

// ---------------------------------------------------------------------------
// Kernel 2: fused edge + coord + node model. One block per (b, i).
// 512 threads = 8 waves; wave w owns output columns [16w, 16w+16).
// ---------------------------------------------------------------------------
__launch_bounds__(512, 4)
__global__ void egcl_main(const float* __restrict__ h,
                          const float* __restrict__ coord,
                          const float* __restrict__ mask,
                          const float* __restrict__ ew1,
                          const float* __restrict__ eb1,
                          const float* __restrict__ eb2,
                          const float* __restrict__ cb1,
                          const float* __restrict__ cw2,
                          const float* __restrict__ nw1,
                          const float* __restrict__ nb1,
                          const float* __restrict__ nw2,
                          const float* __restrict__ nb2,
                          const float* __restrict__ Hs,
                          const float* __restrict__ Ht,
                          const unsigned short* __restrict__ W2T,
                          const unsigned short* __restrict__ Wc1T,
                          const float* __restrict__ msum,
                          float* __restrict__ out_h,
                          float* __restrict__ out_coord) {
    __shared__ __align__(16) unsigned short m1_lds[TJ * LDSTRIDE];
    __shared__ __align__(16) unsigned short m_lds[TJ * LDSTRIDE];
    __shared__ __align__(16) float hb_lds[F_];   // Ht[i] + edge_b1
    __shared__ __align__(16) float w1r_lds[F_];  // edge_w1 radial row
    __shared__ float eb2_lds[F_], cb1_lds[F_], wc2_lds[F_];
    __shared__ float radial_lds[TJ], maskj_lds[TJ], embed_lds[TJ];
    __shared__ float cd_lds[TJ * 3];
    __shared__ float cmi[3], csum_lds[3];
    __shared__ float agg_lds[F_], hin_lds[F_], t_lds[F_];

    const int tid  = threadIdx.x;
    const int wave = tid >> 6;
    const int lane = tid & 63;
    const int quad = lane >> 4;
    const int l15  = lane & 15;

    const int b  = blockIdx.x >> 9;
    const int i  = blockIdx.x & (N_ - 1);
    const int bi = b * N_ + i;
    const float mask_i = mask[bi];

    if (tid < F_) {
        hb_lds[tid]  = Ht[bi * F_ + tid] + eb1[tid];
        w1r_lds[tid] = ew1[2 * F_ * F_ + tid];
        eb2_lds[tid] = eb2[tid];
        cb1_lds[tid] = cb1[tid];
        wc2_lds[tid] = cw2[tid];
    }
    if (tid < 3) {
        cmi[tid] = coord[bi * 3 + tid] * mask_i;
        csum_lds[tid] = 0.f;
    }

    // per-wave register B-fragments (weight slices), bf16 N x K layout
    short8 bW2[4], bWc[4];
    {
        const unsigned short* r2 = W2T  + (wave * 16 + l15) * F_ + quad * 8;
        const unsigned short* rc = Wc1T + (wave * 16 + l15) * F_ + quad * 8;
#pragma unroll
        for (int kk = 0; kk < 4; ++kk) {
            bW2[kk] = *(const short8*)(r2 + kk * 32);
            bWc[kk] = *(const short8*)(rc + kk * 32);
        }
    }

    float agg_reg = 0.f;
    float cs0 = 0.f, cs1 = 0.f, cs2 = 0.f;
    __syncthreads();

    for (int tile = 0; tile < N_ / TJ; ++tile) {
        const int jbase = tile * TJ;
        // ---- stage A: radial / coord-diff / mask_j; zero embed ----
        if (tid < TJ) {
            int j = jbase + tid;
            float mj = mask[b * N_ + j];
            float c0 = coord[(b * N_ + j) * 3 + 0] * mj;
            float c1 = coord[(b * N_ + j) * 3 + 1] * mj;
            float c2 = coord[(b * N_ + j) * 3 + 2] * mj;
            float d0 = cmi[0] - c0, d1 = cmi[1] - c1, d2 = cmi[2] - c2;
            float f2 = mask_i * mj;
            radial_lds[tid] = (d0 * d0 + d1 * d1 + d2 * d2) * f2;
            maskj_lds[tid]  = mj;
            cd_lds[tid * 3 + 0] = d0;
            cd_lds[tid * 3 + 1] = d1;
            cd_lds[tid * 3 + 2] = d2;
        } else if (tid < 2 * TJ) {
            embed_lds[tid - TJ] = 0.f;
        }
        __syncthreads();
        // ---- stage B: m1 = silu(Hs[j] + Ht[i] + radial*w1r + b1) -> bf16 LDS ----
        {
            int fp = tid & 63;       // float2 column index
            int f  = fp * 2;
            int r0 = tid >> 6;       // 0..7
            float2 w1r2 = *(const float2*)&w1r_lds[f];
            float2 hb2  = *(const float2*)&hb_lds[f];
            unsigned* dst32 = (unsigned*)m1_lds;
#pragma unroll
            for (int r = 0; r < 8; ++r) {
                int jr = r0 + r * 8;
                float rad = radial_lds[jr];
                float2 hs2 = *(const float2*)&Hs[(b * N_ + jbase + jr) * F_ + f];
                float x0 = fsilu(hs2.x + hb2.x + rad * w1r2.x);
                float x1 = fsilu(hs2.y + hb2.y + rad * w1r2.y);
                dst32[jr * (LDSTRIDE / 2) + fp] =
                    (unsigned)f2bf(x0) | ((unsigned)f2bf(x1) << 16);
            }
        }
        __syncthreads();
        // ---- stage C: m = silu(m1 @ W2 + b2) * mask2d ; agg += m ; m -> LDS ----
        {
            floatx4 acc[4];
#pragma unroll
            for (int mt = 0; mt < 4; ++mt)
                for (int q = 0; q < 4; ++q) acc[mt][q] = 0.f;
#pragma unroll
            for (int kk = 0; kk < 4; ++kk) {
#pragma unroll
                for (int mt = 0; mt < 4; ++mt) {
                    short8 a = *(const short8*)&m1_lds[(mt * 16 + l15) * LDSTRIDE + kk * 32 + quad * 8];
                    acc[mt] = __builtin_amdgcn_mfma_f32_16x16x32_bf16(a, bW2[kk], acc[mt], 0, 0, 0);
                }
            }
            const int col = wave * 16 + l15;
            const float bias2 = eb2_lds[col];
#pragma unroll
            for (int mt = 0; mt < 4; ++mt) {
#pragma unroll
                for (int rg = 0; rg < 4; ++rg) {
                    int row = mt * 16 + quad * 4 + rg;
                    float v = fsilu(acc[mt][rg] + bias2) * (mask_i * maskj_lds[row]);
                    agg_reg += v;
                    m_lds[row * LDSTRIDE + col] = f2bf(v);
                }
            }
        }
        __syncthreads();
        // ---- stage D: embed = silu(m @ Wc1 + cb1) @ wc2 ----
        {
            floatx4 acc[4];
#pragma unroll
            for (int mt = 0; mt < 4; ++mt)
                for (int q = 0; q < 4; ++q) acc[mt][q] = 0.f;
#pragma unroll
            for (int kk = 0; kk < 4; ++kk) {
#pragma unroll
                for (int mt = 0; mt < 4; ++mt) {
                    short8 a = *(const short8*)&m_lds[(mt * 16 + l15) * LDSTRIDE + kk * 32 + quad * 8];
                    acc[mt] = __builtin_amdgcn_mfma_f32_16x16x32_bf16(a, bWc[kk], acc[mt], 0, 0, 0);
                }
            }
            const int col = wave * 16 + l15;
            const float bias = cb1_lds[col];
            const float w2c  = wc2_lds[col];
#pragma unroll
            for (int mt = 0; mt < 4; ++mt) {
#pragma unroll
                for (int rg = 0; rg < 4; ++rg) {
                    float p = fsilu(acc[mt][rg] + bias) * w2c;
                    p += __shfl_xor(p, 1);
                    p += __shfl_xor(p, 2);
                    p += __shfl_xor(p, 4);
                    p += __shfl_xor(p, 8);
                    if (l15 == 0) atomicAdd(&embed_lds[mt * 16 + quad * 4 + rg], p);
                }
            }
        }
        __syncthreads();
        // ---- stage E: csum += cd * embed * mask2d^2 ----
        if (tid < TJ) {
            float e  = embed_lds[tid];
            float f2 = mask_i * maskj_lds[tid];
            float w  = e * f2 * f2;
            cs0 += cd_lds[tid * 3 + 0] * w;
            cs1 += cd_lds[tid * 3 + 1] * w;
            cs2 += cd_lds[tid * 3 + 2] * w;
        }
        __syncthreads();
    }

    // ---- epilogue: reductions ----
    {
        float a = agg_reg;
        a += __shfl_xor(a, 16);
        a += __shfl_xor(a, 32);
        if (lane < 16) agg_lds[wave * 16 + l15] = a;
    }
    if (tid < TJ) {
        atomicAdd(&csum_lds[0], cs0);
        atomicAdd(&csum_lds[1], cs1);
        atomicAdd(&csum_lds[2], cs2);
    }
    if (tid < F_) hin_lds[tid] = h[bi * F_ + tid] * mask_i;
    __syncthreads();

    // ---- node model layer 1: t = silu([h_m, agg]*mask_i @ nw1 + nb1) ----
    if (tid < F_) {
        float s = nb1[tid];
#pragma unroll 4
        for (int k = 0; k < F_; ++k)
            s += (hin_lds[k] * mask_i) * nw1[k * F_ + tid];
#pragma unroll 4
        for (int k = 0; k < F_; ++k)
            s += (agg_lds[k] * mask_i) * nw1[(F_ + k) * F_ + tid];
        t_lds[tid] = fsilu(s);
    }
    __syncthreads();
    // ---- node layer 2 + residual; coord output ----
    if (tid < F_) {
        float s = nb2[tid];
#pragma unroll 4
        for (int k = 0; k < F_; ++k)
            s += t_lds[k] * nw2[k * F_ + tid];
        out_h[bi * F_ + tid] = (hin_lds[tid] + s) * mask_i;
    } else if (tid >= 128 && tid < 131) {
        int d = tid - 128;
        float denom = mask_i * msum[b] + 1e-10f;
        out_coord[bi * 3 + d] =
            (cmi[d] + csum_lds[d] * __builtin_amdgcn_rcpf(denom)) * mask_i;
    }
}

// ---------------------------------------------------------------------------
extern "C" void kernel_launch(void* const* d_in, const int* in_sizes, int n_in,
                              void* d_out, int out_size, void* d_ws, size_t ws_size,
                              hipStream_t stream) {
    const float* h     = (const float*)d_in[0];
    const float* coord = (const float*)d_in[1];
    const float* mask  = (const float*)d_in[2];
    const float* ew1   = (const float*)d_in[3];
    const float* eb1   = (const float*)d_in[4];
    const float* ew2   = (const float*)d_in[5];
    const float* eb2   = (const float*)d_in[6];
    const float* nw1   = (const float*)d_in[7];
    const float* nb1   = (const float*)d_in[8];
    const float* nw2   = (const float*)d_in[9];
    const float* nb2   = (const float*)d_in[10];
    const float* cw1   = (const float*)d_in[11];
    const float* cb1   = (const float*)d_in[12];
    const float* cw2   = (const float*)d_in[13];

    float* Hs = (float*)d_ws;                                  // 131072 f32
    float* Ht = Hs + B_ * N_ * F_;                             // 131072 f32
    unsigned short* W2T  = (unsigned short*)(Ht + B_ * N_ * F_);  // 16384 bf16
    unsigned short* Wc1T = W2T + F_ * F_;                      // 16384 bf16
    float* msum = (float*)(Wc1T + F_ * F_);                    // 2 f32

    float* out_h     = (float*)d_out;
    float* out_coord = out_h + B_ * N_ * F_;

    egcl_prep<<<B_ * N_ + F_ + 1, 128, 0, stream>>>(h, mask, ew1, ew2, cw1,
                                                    Hs, Ht, W2T, Wc1T, msum);
    egcl_main<<<B_ * N_, 512, 0, stream>>>(h, coord, mask, ew1, eb1, eb2, cb1, cw2,
                                           nw1, nb1, nw2, nb2,
                                           Hs, Ht, W2T, Wc1T, msum,
                                           out_h, out_coord);
}

// Round 2
// 234.421 us; speedup vs baseline: 1.1747x; 1.1747x over previous
//
#include <hip/hip_runtime.h>

#define B_ 2
#define N_ 512
#define F_ 128
#define BN (B_ * N_)

typedef __attribute__((ext_vector_type(8))) short short8;
typedef __attribute__((ext_vector_type(4))) float floatx4;

__device__ __forceinline__ float fsilu(float x) {
    float e = __expf(-x);
    return x * __builtin_amdgcn_rcpf(1.0f + e);
}
__device__ __forceinline__ unsigned f2bf(float x) {
    unsigned u = __float_as_uint(x);
    u += 0x7fffu + ((u >> 16) & 1u);  // RNE
    return u >> 16;
}
__device__ __forceinline__ unsigned pack2(float a, float b) {
    return f2bf(a) | (f2bf(b) << 16);
}

// ---------------------------------------------------------------------------
// Prep: Hs/Ht (edge_w1 decomposition), weights pre-packed into MFMA A-frag
// order (Wt[k][fo] per lane chunk), msum.
//   blocks [0,128): Hs/Ht, 8 rows each.  [128,136): W2A pack. [136,144): WcA.
//   block 144: msum.
// ---------------------------------------------------------------------------
__global__ __launch_bounds__(256) void egcl_prep(
        const float* __restrict__ h, const float* __restrict__ mask,
        const float* __restrict__ ew1, const float* __restrict__ ew2,
        const float* __restrict__ cw1,
        float* __restrict__ Hs, float* __restrict__ Ht,
        unsigned short* __restrict__ W2A, unsigned short* __restrict__ WcA,
        float* __restrict__ msum) {
    __shared__ float sh[8][F_];
    const int blk = blockIdx.x, tid = threadIdx.x;
    if (blk < BN / 8) {
        const int r0 = blk * 8;
        const int col = tid & 127, half = tid >> 7;
        if (half == 0) {
#pragma unroll
            for (int r = 0; r < 8; ++r)
                sh[r][col] = h[(r0 + r) * F_ + col] * mask[r0 + r];
        }
        __syncthreads();
        const float* W = ew1 + half * F_ * F_;
        float acc[8] = {0.f, 0.f, 0.f, 0.f, 0.f, 0.f, 0.f, 0.f};
#pragma unroll 4
        for (int k = 0; k < F_; ++k) {
            float w = W[k * F_ + col];
#pragma unroll
            for (int r = 0; r < 8; ++r) acc[r] += sh[r][k] * w;
        }
        float* dst = half ? Ht : Hs;
#pragma unroll
        for (int r = 0; r < 8; ++r) dst[(r0 + r) * F_ + col] = acc[r];
    } else if (blk < BN / 8 + 16) {
        const int wsel = (blk - BN / 8) >> 3;
        const int cidx = ((blk - BN / 8) & 7) * 256 + tid;  // 0..2047
        const float* src = wsel ? cw1 : ew2;
        unsigned short* dst = wsel ? WcA : W2A;
        const int mt = cidx >> 8, kk = (cidx >> 6) & 3, lane = cidx & 63;
        const int q = lane >> 4, l = lane & 15;
#pragma unroll
        for (int t = 0; t < 8; ++t)
            dst[cidx * 8 + t] =
                (unsigned short)f2bf(src[(kk * 32 + q * 8 + t) * F_ + mt * 16 + l]);
    } else {
        float* sm = (float*)sh;
        for (int bb = 0; bb < B_; ++bb) {
            if (tid < 128) {
                float s = 0.f;
#pragma unroll
                for (int q = 0; q < N_ / 128; ++q) s += mask[bb * N_ + tid + q * 128];
                sm[tid] = s;
            }
            __syncthreads();
            if (tid == 0) {
                float s = 0.f;
                for (int k = 0; k < 128; ++k) s += sm[k];
                msum[bb] = s;
            }
            __syncthreads();
        }
    }
}

// ---------------------------------------------------------------------------
// Main: one block per (b,i), 8 waves, each wave owns 64 j-rows (4 chunks of
// 16). No barriers inside the chunk loop. Both GEMMs in transposed form so
// m1 / m serve directly as MFMA B-operands; weights are A-operands from LDS.
// ---------------------------------------------------------------------------
__global__ __launch_bounds__(512, 2) void egcl_main(
        const float* __restrict__ h, const float* __restrict__ coord,
        const float* __restrict__ mask,
        const float* __restrict__ eb1, const float* __restrict__ eb2,
        const float* __restrict__ cb1, const float* __restrict__ cw2,
        const float* __restrict__ nw1, const float* __restrict__ nb1,
        const float* __restrict__ nw2, const float* __restrict__ nb2,
        const float* __restrict__ ew1,
        const float* __restrict__ Hs, const float* __restrict__ Ht,
        const unsigned short* __restrict__ W2Ag,
        const unsigned short* __restrict__ WcAg,
        const float* __restrict__ msum,
        float* __restrict__ out_h, float* __restrict__ out_coord) {
    extern __shared__ char smem[];
    unsigned short* w2a = (unsigned short*)smem;   // 16384 shorts
    unsigned short* wca = w2a + 16384;             // 16384 shorts
    unsigned short* scr = wca + 16384;             // 8 waves * 2048 shorts
    float* eb2s = (float*)(scr + 16384);
    float* cb1s = eb2s + F_;
    float* wc2s = cb1s + F_;
    float* aggs = wc2s + F_;
    float* hins = aggs + F_;
    float* tss  = hins + F_;
    float* csums = tss + F_;  // 3 floats (+ pad)

    const int tid = threadIdx.x;
    const int wave = tid >> 6, lane = tid & 63;
    const int quad = lane >> 4, l15 = lane & 15;
    const int b = blockIdx.x >> 9, i = blockIdx.x & (N_ - 1);
    const int bi = b * N_ + i;
    const float mask_i = mask[bi];

    // ---- stage weights (already in A-fragment order) + small tables ----
    {
        const short8* g2 = (const short8*)W2Ag;
        const short8* gc = (const short8*)WcAg;
        short8* l2 = (short8*)w2a;
        short8* lc = (short8*)wca;
#pragma unroll
        for (int r = 0; r < 4; ++r) {
            l2[tid + r * 512] = g2[tid + r * 512];
            lc[tid + r * 512] = gc[tid + r * 512];
        }
    }
    if (tid < F_) {
        eb2s[tid] = eb2[tid];
        cb1s[tid] = cb1[tid];
        wc2s[tid] = cw2[tid];
        aggs[tid] = 0.f;
        hins[tid] = h[bi * F_ + tid] * mask_i;
    }
    if (tid < 3) csums[tid] = 0.f;

    const float cmi0 = coord[bi * 3 + 0] * mask_i;
    const float cmi1 = coord[bi * 3 + 1] * mask_i;
    const float cmi2 = coord[bi * 3 + 2] * mask_i;

    // per-lane Ht[i]+eb1 and w1_radial fragments (cols kk*32+quad*8 .. +8)
    float hbv[4][8], w1v[4][8];
#pragma unroll
    for (int kk = 0; kk < 4; ++kk) {
        const floatx4* tp = (const floatx4*)(Ht + bi * F_ + kk * 32 + quad * 8);
        const floatx4* ep = (const floatx4*)(eb1 + kk * 32 + quad * 8);
        const floatx4* wp = (const floatx4*)(ew1 + 2 * F_ * F_ + kk * 32 + quad * 8);
        floatx4 t0 = tp[0], t1 = tp[1];
        floatx4 e0 = ep[0], e1 = ep[1];
        floatx4 w0 = wp[0], w1 = wp[1];
#pragma unroll
        for (int t = 0; t < 4; ++t) {
            hbv[kk][t] = t0[t] + e0[t];
            hbv[kk][4 + t] = t1[t] + e1[t];
            w1v[kk][t] = w0[t];
            w1v[kk][4 + t] = w1[t];
        }
    }

    float agg[8][4];
#pragma unroll
    for (int mt = 0; mt < 8; ++mt)
#pragma unroll
        for (int rg = 0; rg < 4; ++rg) agg[mt][rg] = 0.f;
    float cs0 = 0.f, cs1 = 0.f, cs2 = 0.f;

    __syncthreads();  // weights/tables visible; waves now run free

    unsigned short* myscr = scr + wave * 2048;

    for (int c = 0; c < 4; ++c) {
        const int jr = wave * 64 + c * 16 + l15;
        const int bj = b * N_ + jr;
        const float mj = mask[bj];
        const float d0 = cmi0 - coord[bj * 3 + 0] * mj;
        const float d1 = cmi1 - coord[bj * 3 + 1] * mj;
        const float d2 = cmi2 - coord[bj * 3 + 2] * mj;
        const float f2 = mask_i * mj;
        const float rad = (d0 * d0 + d1 * d1 + d2 * d2) * f2;

        // ---- m1 B-fragments: lane computes m1[j=l15][k=kk*32+quad*8+t] ----
        short8 bfr[4];
#pragma unroll
        for (int kk = 0; kk < 4; ++kk) {
            const floatx4* hp = (const floatx4*)(Hs + bj * F_ + kk * 32 + quad * 8);
            floatx4 h0 = hp[0], h1 = hp[1];
            float x[8];
#pragma unroll
            for (int t = 0; t < 4; ++t) {
                x[t]     = fsilu(h0[t] + hbv[kk][t]     + rad * w1v[kk][t]);
                x[4 + t] = fsilu(h1[t] + hbv[kk][4 + t] + rad * w1v[kk][4 + t]);
            }
            union { short8 s; unsigned u[4]; } bu;
            bu.u[0] = pack2(x[0], x[1]);
            bu.u[1] = pack2(x[2], x[3]);
            bu.u[2] = pack2(x[4], x[5]);
            bu.u[3] = pack2(x[6], x[7]);
            bfr[kk] = bu.s;
        }

        // ---- GEMM1': m[j][fo] = sum_k W2[k][fo] * m1[j][k] ----
        floatx4 acc[8];
#pragma unroll
        for (int mt = 0; mt < 8; ++mt)
#pragma unroll
            for (int rg = 0; rg < 4; ++rg) acc[mt][rg] = 0.f;
#pragma unroll
        for (int kk = 0; kk < 4; ++kk) {
#pragma unroll
            for (int mt = 0; mt < 8; ++mt) {
                short8 wf = *(const short8*)&w2a[((mt * 4 + kk) * 64 + lane) * 8];
                acc[mt] = __builtin_amdgcn_mfma_f32_16x16x32_bf16(wf, bfr[kk], acc[mt], 0, 0, 0);
            }
        }

        // ---- epilogue1: silu+mask, agg+=, write m to per-wave swizzled scratch ----
#pragma unroll
        for (int mt = 0; mt < 8; ++mt) {
            floatx4 ebv = *(const floatx4*)&eb2s[mt * 16 + quad * 4];
            float v0 = fsilu(acc[mt][0] + ebv[0]) * f2;
            float v1 = fsilu(acc[mt][1] + ebv[1]) * f2;
            float v2 = fsilu(acc[mt][2] + ebv[2]) * f2;
            float v3 = fsilu(acc[mt][3] + ebv[3]) * f2;
            agg[mt][0] += v0; agg[mt][1] += v1; agg[mt][2] += v2; agg[mt][3] += v3;
            uint2 pp;
            pp.x = pack2(v0, v1);
            pp.y = pack2(v2, v3);
            *(uint2*)&myscr[l15 * 128 + (((2 * mt + (quad >> 1)) ^ l15) << 3) + ((quad & 1) << 2)] = pp;
        }

        // ---- GEMM2': pre[fo2][j] = sum_k Wc1[k][fo2] * m[j][k] ----
        floatx4 ac2[8];
#pragma unroll
        for (int mt = 0; mt < 8; ++mt)
#pragma unroll
            for (int rg = 0; rg < 4; ++rg) ac2[mt][rg] = 0.f;
#pragma unroll
        for (int kk = 0; kk < 4; ++kk) {
            short8 b2 = *(const short8*)&myscr[l15 * 128 + (((4 * kk + quad) ^ l15) << 3)];
#pragma unroll
            for (int mt = 0; mt < 8; ++mt) {
                short8 wf = *(const short8*)&wca[((mt * 4 + kk) * 64 + lane) * 8];
                ac2[mt] = __builtin_amdgcn_mfma_f32_16x16x32_bf16(wf, b2, ac2[mt], 0, 0, 0);
            }
        }

        // ---- epilogue2: embed[j] then coord accumulation ----
        float es = 0.f;
#pragma unroll
        for (int mt = 0; mt < 8; ++mt) {
            floatx4 cbv = *(const floatx4*)&cb1s[mt * 16 + quad * 4];
            floatx4 wcv = *(const floatx4*)&wc2s[mt * 16 + quad * 4];
#pragma unroll
            for (int rg = 0; rg < 4; ++rg)
                es += fsilu(ac2[mt][rg] + cbv[rg]) * wcv[rg];
        }
        es += __shfl_xor(es, 16);
        es += __shfl_xor(es, 32);  // embed[j=jr], replicated across quads
        const float w = es * f2 * f2;
        cs0 += d0 * w; cs1 += d1 * w; cs2 += d2 * w;
    }

    // ---- cross-lane/wave reductions ----
#pragma unroll
    for (int mt = 0; mt < 8; ++mt)
#pragma unroll
        for (int rg = 0; rg < 4; ++rg) {
            float v = agg[mt][rg];
            v += __shfl_xor(v, 1);
            v += __shfl_xor(v, 2);
            v += __shfl_xor(v, 4);
            v += __shfl_xor(v, 8);
            agg[mt][rg] = v;
        }
    if (l15 == 0) {
#pragma unroll
        for (int mt = 0; mt < 8; ++mt)
#pragma unroll
            for (int rg = 0; rg < 4; ++rg)
                atomicAdd(&aggs[mt * 16 + quad * 4 + rg], agg[mt][rg]);
    }
    {
        cs0 += __shfl_xor(cs0, 1); cs0 += __shfl_xor(cs0, 2);
        cs0 += __shfl_xor(cs0, 4); cs0 += __shfl_xor(cs0, 8);
        cs1 += __shfl_xor(cs1, 1); cs1 += __shfl_xor(cs1, 2);
        cs1 += __shfl_xor(cs1, 4); cs1 += __shfl_xor(cs1, 8);
        cs2 += __shfl_xor(cs2, 1); cs2 += __shfl_xor(cs2, 2);
        cs2 += __shfl_xor(cs2, 4); cs2 += __shfl_xor(cs2, 8);
        if (lane == 0) {
            atomicAdd(&csums[0], cs0);
            atomicAdd(&csums[1], cs1);
            atomicAdd(&csums[2], cs2);
        }
    }
    __syncthreads();

    // ---- node MLP + outputs ----
    if (tid < F_) {
        float s = nb1[tid];
#pragma unroll 8
        for (int k = 0; k < F_; ++k)
            s += (hins[k] * mask_i) * nw1[k * F_ + tid];
#pragma unroll 8
        for (int k = 0; k < F_; ++k)
            s += (aggs[k] * mask_i) * nw1[(F_ + k) * F_ + tid];
        tss[tid] = fsilu(s);
    }
    __syncthreads();
    if (tid < F_) {
        float s = nb2[tid];
#pragma unroll 8
        for (int k = 0; k < F_; ++k)
            s += tss[k] * nw2[k * F_ + tid];
        out_h[bi * F_ + tid] = (hins[tid] + s) * mask_i;
    } else if (tid < F_ + 3) {
        const int d = tid - F_;
        const float denom = mask_i * msum[b] + 1e-10f;
        const float cm = (d == 0) ? cmi0 : ((d == 1) ? cmi1 : cmi2);
        out_coord[bi * 3 + d] =
            (cm + csums[d] * __builtin_amdgcn_rcpf(denom)) * mask_i;
    }
}

// ---------------------------------------------------------------------------
extern "C" void kernel_launch(void* const* d_in, const int* in_sizes, int n_in,
                              void* d_out, int out_size, void* d_ws, size_t ws_size,
                              hipStream_t stream) {
    const float* h     = (const float*)d_in[0];
    const float* coord = (const float*)d_in[1];
    const float* mask  = (const float*)d_in[2];
    const float* ew1   = (const float*)d_in[3];
    const float* eb1   = (const float*)d_in[4];
    const float* ew2   = (const float*)d_in[5];
    const float* eb2   = (const float*)d_in[6];
    const float* nw1   = (const float*)d_in[7];
    const float* nb1   = (const float*)d_in[8];
    const float* nw2   = (const float*)d_in[9];
    const float* nb2   = (const float*)d_in[10];
    const float* cw1   = (const float*)d_in[11];
    const float* cb1   = (const float*)d_in[12];
    const float* cw2   = (const float*)d_in[13];

    float* Hs = (float*)d_ws;                                     // 131072 f32
    float* Ht = Hs + BN * F_;                                     // 131072 f32
    unsigned short* W2A = (unsigned short*)(Ht + BN * F_);        // 16384 u16
    unsigned short* WcA = W2A + F_ * F_;                          // 16384 u16
    float* msum = (float*)(WcA + F_ * F_);                        // 2 f32

    float* out_h = (float*)d_out;
    float* out_coord = out_h + BN * F_;

    egcl_prep<<<BN / 8 + 17, 256, 0, stream>>>(h, mask, ew1, ew2, cw1,
                                               Hs, Ht, W2A, WcA, msum);

    const size_t smem_bytes = (size_t)(16384 * 3) * 2 + (F_ * 6 + 4) * 4;
    egcl_main<<<BN, 512, smem_bytes, stream>>>(
        h, coord, mask, eb1, eb2, cb1, cw2, nw1, nb1, nw2, nb2, ew1,
        Hs, Ht, W2A, WcA, msum, out_h, out_coord);
}